// Round 8
// baseline (120.757 us; speedup 1.0000x reference)
//
#include <hip/hip_runtime.h>
#include <cstdint>

typedef __attribute__((ext_vector_type(8))) short bf16x8;
typedef __attribute__((ext_vector_type(4))) float f32x4;

#define BN_NB 256
#define LRELU_SLOPE 0.1f

__device__ __forceinline__ float bf2f(ushort h) {
    union { uint u; float v; } x; x.u = ((uint)h) << 16; return x.v;
}
__device__ __forceinline__ ushort f2bf(float f) {
    union { float v; uint u; } x; x.v = f;
    const uint r = (x.u + 0x7FFFu + ((x.u >> 16) & 1u)) >> 16;  // RNE
    return (ushort)r;
}

// m204 bijective XCD swizzle: contiguous grid chunk per XCD (8 XCDs).
__device__ __forceinline__ int xcd_swizzle(int bid, int nwg) {
    const int q = nwg >> 3, r = nwg & 7;
    const int xcd = bid & 7, local = bid >> 3;
    return (xcd < r ? xcd * (q + 1) : r * (q + 1) + (xcd - r) * q) + local;
}

// async 16B global->LDS (wave-uniform LDS base + lane*16)
__device__ __forceinline__ void gload_lds16(const void* g, void* l) {
    __builtin_amdgcn_global_load_lds((const __attribute__((address_space(1))) void*)g,
                                     (__attribute__((address_space(3))) void*)l, 16, 0, 0);
}

// ---------------------------------------------------------------------------
// x (fp32) -> bf16, vectorized
// ---------------------------------------------------------------------------
__global__ __launch_bounds__(256) void cvt_bf16(const float* __restrict__ in,
                                                ushort* __restrict__ out, int n4)
{
    for (int i = blockIdx.x * 256 + threadIdx.x; i < n4; i += gridDim.x * 256) {
        const float4 v = reinterpret_cast<const float4*>(in)[i];
        ushort4 o;
        o.x = f2bf(v.x); o.y = f2bf(v.y); o.z = f2bf(v.z); o.w = f2bf(v.w);
        reinterpret_cast<ushort4*>(out)[i] = o;
    }
}

// ---------------------------------------------------------------------------
// Zero the sentinel rows appended to each feature table.
// ---------------------------------------------------------------------------
__global__ __launch_bounds__(128) void zero_rows(ushort* __restrict__ xbz,
                                                 ushort* __restrict__ f1z,
                                                 ushort* __restrict__ f2z)
{
    const int t = threadIdx.x;
    if (t < 96) xbz[t] = 0;
    if (t < 64) { f1z[t] = 0; f2z[t] = 0; }
}

// ---------------------------------------------------------------------------
// Pack W[K][CIN][64] fp32 -> bf16 B-fragments.
// Slice s = (tap*KB + kb)*4 + cb; lane l holds W[kb*32+(l>>4)*8+e][cb*16+(l&15)].
// ---------------------------------------------------------------------------
template<int K, int CIN>
__global__ __launch_bounds__(256) void pack_W(const float* __restrict__ W,
                                              ushort* __restrict__ Bp)
{
    constexpr int KB = CIN / 32;
    const int t = blockIdx.x * 256 + threadIdx.x;
    if (t >= K * KB * 4 * 64) return;
    const int l = t & 63;
    const int s = t >> 6;
    const int cb = s & 3;
    const int kk = s >> 2;
    const int kb = kk % KB;
    const int tap = kk / KB;
    const int k0 = kb * 32 + (l >> 4) * 8;
    const int col = cb * 16 + (l & 15);
    bf16x8 v;
#pragma unroll
    for (int e = 0; e < 8; ++e)
        v[e] = (short)f2bf(W[((size_t)tap * CIN + k0 + e) * 64 + col]);
    *reinterpret_cast<bf16x8*>(Bp + (size_t)t * 8) = v;
}

// ---------------------------------------------------------------------------
// Sparse conv via MFMA 16x16x32 bf16. B staged into LDS (double-buffered,
// global_load_lds); A gathered per-lane from global. T4 counted-vmcnt
// barrier: each round ends with s_waitcnt vmcnt(KB) + raw s_barrier --
// drains only this wave's B-stage (cross-wave LDS visibility) while the
// scattered next-tap A-gathers stay in flight ACROSS the barrier.
// FIFO order per round: [stage(t+1) x KB, gatherA(t+1) x KB]; the
// compiler's automatic wait on A(t) registers in COMPUTE drains all older
// ops, guaranteeing buf[t]'s stage completed before its ds_reads.
// Block: 256 thr = 4 waves, 64 output rows; wave w: rows w*16..+15 x 64 cols.
// ---------------------------------------------------------------------------
template<int K, int CIN, bool LEAKY, bool OUTF32>
__global__ __launch_bounds__(256) void sconv_dg(
    const ushort* __restrict__ fin,      // [nin+1][CIN], row nin == zeros
    const int* __restrict__ nmap,        // [nout][K]
    const ushort* __restrict__ Bp,       // packed B fragments
    const float* __restrict__ bias,      // [64]
    void* __restrict__ fout, int nout)
{
    constexpr int KB = CIN / 32;       // 32-k blocks per tap
    constexpr int CHUNKS = KB * 4;     // 1KB fragment-chunks per tap slice
    __shared__ int idxc[64 * K];
    __shared__ ushort Bbuf[2][CHUNKS * 512];

    const int tid = threadIdx.x;
    const int l = tid & 63;
    const int w = tid >> 6;            // 0..3
    const int base = xcd_swizzle(blockIdx.x, gridDim.x) * 64;

    // cache this block's nmap rows (coalesced); OOB rows use row 0 (discarded)
    for (int e = tid; e < 64 * K; e += 256) {
        const int r = base + e / K;
        idxc[e] = (r < nout) ? nmap[(size_t)r * K + (e % K)] : 0;
    }
    __syncthreads();

    const int lrow = l & 15;
    const int grp = l >> 4;
    const int myrow = w * 16 + lrow;
    const int koff = grp * 8;          // ushort offset inside a 32-k chunk

    f32x4 acc[4];
#pragma unroll
    for (int cb = 0; cb < 4; ++cb) acc[cb] = (f32x4){0.f, 0.f, 0.f, 0.f};

    // ---- helpers (macros keep all indexing compile-time static) ----
#define STAGE_B(tap, buf)                                                    \
    {                                                                        \
        _Pragma("unroll")                                                    \
        for (int j = 0; j < KB; ++j) {                                       \
            const int c = w * KB + j;                                        \
            gload_lds16(Bp + (size_t)(tap) * CHUNKS * 512 + c * 512 + l * 8, \
                        &Bbuf[buf][c * 512]);                                \
        }                                                                    \
    }

#define GATHER_A(SET, tap)                                                   \
    {                                                                        \
        const size_t idx_ = (size_t)idxc[myrow * K + (tap)];                 \
        const ushort* rp_ = fin + idx_ * CIN + koff;                         \
        _Pragma("unroll")                                                    \
        for (int kb = 0; kb < KB; ++kb)                                      \
            SET[kb] = *reinterpret_cast<const bf16x8*>(rp_ + kb * 32);       \
    }

#define COMPUTE(SET, buf)                                                    \
    {                                                                        \
        _Pragma("unroll")                                                    \
        for (int kb = 0; kb < KB; ++kb) {                                    \
            _Pragma("unroll")                                                \
            for (int cb = 0; cb < 4; ++cb) {                                 \
                const bf16x8 b_ = *reinterpret_cast<const bf16x8*>(          \
                    &Bbuf[buf][(kb * 4 + cb) * 512 + l * 8]);                \
                acc[cb] = __builtin_amdgcn_mfma_f32_16x16x32_bf16(           \
                    SET[kb], b_, acc[cb], 0, 0, 0);                          \
            }                                                                \
        }                                                                    \
    }

    // counted-vmcnt barrier: drain own B-stage, keep A-gathers in flight
#define PIPE_BARRIER()                                                       \
    {                                                                        \
        __builtin_amdgcn_sched_barrier(0);                                   \
        asm volatile("s_waitcnt vmcnt(%0)" :: "n"(KB) : "memory");           \
        __builtin_amdgcn_s_barrier();                                        \
        __builtin_amdgcn_sched_barrier(0);                                   \
    }

    bf16x8 aA[KB], aB[KB];
    STAGE_B(0, 0);
    GATHER_A(aA, 0);
    PIPE_BARRIER();    // buf0 stage drained by its producer waves; A(0) in flight

    for (int kp = 0; kp < K; kp += 2) {
        // round kp: stage kp+1 into buf1 + gather A(kp+1), compute tap kp from buf0
        if (kp + 1 < K) { STAGE_B(kp + 1, 1); GATHER_A(aB, kp + 1); }
        COMPUTE(aA, 0);
        if (kp + 1 < K) {
            PIPE_BARRIER();
            // round kp+1: stage kp+2 into buf0 + gather A(kp+2), compute from buf1
            if (kp + 2 < K) { STAGE_B(kp + 2, 0); GATHER_A(aA, kp + 2); }
            COMPUTE(aB, 1);
            if (kp + 2 < K) PIPE_BARRIER();
        }
    }
#undef STAGE_B
#undef GATHER_A
#undef COMPUTE
#undef PIPE_BARRIER

    // ---- epilogue: D row = grp*4+i, col = cb*16+lrow (m89-verified) ----
    const int r0 = base + w * 16 + grp * 4;
#pragma unroll
    for (int cb = 0; cb < 4; ++cb) {
        const int col = cb * 16 + lrow;
        const float bcol = bias[col];
#pragma unroll
        for (int i = 0; i < 4; ++i) {
            const int r = r0 + i;
            if (r < nout) {
                float o = acc[cb][i] + bcol;
                if (LEAKY) o = o >= 0.f ? o : LRELU_SLOPE * o;
                if (OUTF32) reinterpret_cast<float*>(fout)[(size_t)r * 64 + col] = o;
                else        reinterpret_cast<ushort*>(fout)[(size_t)r * 64 + col] = f2bf(o);
            }
        }
    }
}

// ---------------------------------------------------------------------------
// BatchNorm stage 1 (bf16 input): deterministic per-block partial sum/sumsq.
// ---------------------------------------------------------------------------
__global__ __launch_bounds__(256) void bn_partial(const ushort* __restrict__ f2v, int n2,
                                                  float* __restrict__ partials)
{
    const int c = threadIdx.x & 63;
    const int g = threadIdx.x >> 6;
    float s = 0.f, ss = 0.f;
    for (int r = blockIdx.x * 4 + g; r < n2; r += gridDim.x * 4) {
        const float v = bf2f(f2v[(size_t)r * 64 + c]);
        s += v;
        ss = fmaf(v, v, ss);
    }
    __shared__ float red[4][128];
    red[g][c] = s;
    red[g][64 + c] = ss;
    __syncthreads();
    if (g == 0) {
        partials[(size_t)blockIdx.x * 128 + c] =
            red[0][c] + red[1][c] + red[2][c] + red[3][c];
        partials[(size_t)blockIdx.x * 128 + 64 + c] =
            red[0][64 + c] + red[1][64 + c] + red[2][64 + c] + red[3][64 + c];
    }
}

// ---------------------------------------------------------------------------
// BatchNorm stage 2: PARALLEL final reduce (1024 thr = 8 row-groups x 128 cols)
// -> per-channel affine a,b with scale folded.
// ---------------------------------------------------------------------------
__global__ __launch_bounds__(1024) void bn_finalize(const float* __restrict__ partials, int n2,
                                                    const float* __restrict__ gamma,
                                                    const float* __restrict__ beta,
                                                    const float* __restrict__ scale,
                                                    float* __restrict__ affA, float* __restrict__ affB)
{
    const int t = threadIdx.x;
    const int col = t & 127;
    const int g = t >> 7;
    float s = 0.f;
#pragma unroll
    for (int b = g; b < BN_NB; b += 8)
        s += partials[(size_t)b * 128 + col];
    __shared__ float red[8][128];
    red[g][col] = s;
    __syncthreads();
    if (g == 0) {
        float S = red[0][col];
#pragma unroll
        for (int i = 1; i < 8; ++i) S += red[i][col];
        red[0][col] = S;
    }
    __syncthreads();
    if (t < 64) {
        const float S = red[0][t];
        const float SS = red[0][64 + t];
        const float inv_n = 1.f / (float)n2;
        const float mu = S * inv_n;
        const float var = fmaxf(SS * inv_n - mu * mu, 0.f);
        const float rs = rsqrtf(var + 1e-5f);
        const float sc = scale[0];
        const float ga = gamma[t];
        affA[t] = rs * ga * sc;
        affB[t] = (beta[t] - mu * rs * ga) * sc;
    }
}

// ---------------------------------------------------------------------------
// In-place BN affine on f2 (bf16): f2 = f2*a + b. Elementwise, deterministic.
// ---------------------------------------------------------------------------
__global__ __launch_bounds__(256) void aff_apply(ushort* __restrict__ f2, int nchunk,
                                                 const float* __restrict__ affA,
                                                 const float* __restrict__ affB)
{
    for (int i = blockIdx.x * 256 + threadIdx.x; i < nchunk; i += gridDim.x * 256) {
        const int c = i & 7;  // chunk-within-row
        bf16x8 v = *reinterpret_cast<const bf16x8*>(f2 + (size_t)i * 8);
#pragma unroll
        for (int j = 0; j < 8; ++j)
            v[j] = (short)f2bf(fmaf(bf2f((ushort)v[j]), affA[c * 8 + j], affB[c * 8 + j]));
        *reinterpret_cast<bf16x8*>(f2 + (size_t)i * 8) = v;
    }
}

extern "C" void kernel_launch(void* const* d_in, const int* in_sizes, int n_in,
                              void* d_out, int out_size, void* d_ws, size_t ws_size,
                              hipStream_t stream)
{
    const float* x     = (const float*)d_in[0];
    const float* W1    = (const float*)d_in[1];
    const float* b1    = (const float*)d_in[2];
    const float* W2    = (const float*)d_in[3];
    const float* b2    = (const float*)d_in[4];
    const float* W3    = (const float*)d_in[5];
    const float* b3    = (const float*)d_in[6];
    const float* gamma = (const float*)d_in[7];
    const float* beta  = (const float*)d_in[8];
    const float* scale = (const float*)d_in[9];
    const int* nmap1   = (const int*)d_in[10];
    const int* nmap2   = (const int*)d_in[11];
    const int* nmap3   = (const int*)d_in[12];

    const int N  = in_sizes[0] / 96;    // stride-1 points
    const int N2 = in_sizes[11] / 8;    // stride-2 points

    // workspace (all regions 16B-aligned; +1 zero row per feature table)
    ushort* xb  = (ushort*)d_ws;                    // [N+1,96] bf16
    ushort* f1  = xb + (size_t)(N + 1) * 96;        // [N+1,64] bf16
    ushort* f2  = f1 + (size_t)(N + 1) * 64;        // [N2+1,64] bf16
    ushort* Bp1 = f2 + (size_t)(N2 + 1) * 64;       // 27*96*64 bf16
    ushort* Bp2 = Bp1 + 27 * 96 * 64;               // 8*64*64
    ushort* Bp3 = Bp2 + 8 * 64 * 64;                // 27*64*64
    float* partials = (float*)(Bp3 + 27 * 64 * 64); // [BN_NB,128]
    float* affA = partials + (size_t)BN_NB * 128;   // [64]
    float* affB = affA + 64;                        // [64]
    float* out  = (float*)d_out;                    // [N2,64] fp32

    // sentinel zero rows + input conversion + weight packing
    zero_rows<<<1, 128, 0, stream>>>(xb + (size_t)N * 96, f1 + (size_t)N * 64,
                                     f2 + (size_t)N2 * 64);
    cvt_bf16<<<2048, 256, 0, stream>>>(x, xb, N * 96 / 4);
    pack_W<27, 96><<<(27 * 3 * 4 * 64 + 255) / 256, 256, 0, stream>>>(W1, Bp1);
    pack_W<8, 64><<<(8 * 2 * 4 * 64 + 255) / 256, 256, 0, stream>>>(W2, Bp2);
    pack_W<27, 64><<<(27 * 2 * 4 * 64 + 255) / 256, 256, 0, stream>>>(W3, Bp3);

    // conv1: k=27, 96->64, leaky
    sconv_dg<27, 96, true, false><<<(N + 63) / 64, 256, 0, stream>>>(
        xb, nmap1, Bp1, b1, f1, N);
    // conv2: k=8, 64->64, leaky (downsample)
    sconv_dg<8, 64, true, false><<<(N2 + 63) / 64, 256, 0, stream>>>(
        f1, nmap2, Bp2, b2, f2, N2);
    // batchnorm stats (two-stage, deterministic) + in-place affine
    bn_partial<<<BN_NB, 256, 0, stream>>>(f2, N2, partials);
    bn_finalize<<<1, 1024, 0, stream>>>(partials, N2, gamma, beta, scale, affA, affB);
    aff_apply<<<2048, 256, 0, stream>>>(f2, N2 * 8, affA, affB);
    // conv3: k=27, 64->64, fp32 out
    sconv_dg<27, 64, false, true><<<(N2 + 63) / 64, 256, 0, stream>>>(
        f2, nmap3, Bp3, b3, out, N2);
}